// Round 1
// baseline (15049.464 us; speedup 1.0000x reference)
//
#include <hip/hip_runtime.h>
#include <cstdio>
#include <cstdint>

#define N_NODES 100000
#define N_EDGES 600000
#define DIM     128
#define NSETS   3
#define NLAYERS 2
#define NGRAPH  64
#define NPASS   2

static __device__ __forceinline__ float bf2f(unsigned short u) {
    return __uint_as_float(((uint32_t)u) << 16);
}
static __device__ __forceinline__ unsigned short f2bf(float f) {
    uint32_t u = __float_as_uint(f);
    uint32_t r = (u + 0x7FFFu + ((u >> 16) & 1u)) >> 16;
    return (unsigned short)r;
}
static __device__ __forceinline__ float sigmoidf_(float x) {
    return 1.0f / (1.0f + __expf(-x));
}

// ---------------- dtype detection ----------------
// If the buffer really holds fp32, its low 16-bit halves reinterpreted as bf16
// have uniform-random exponents -> max |v| is astronomically large. Genuine
// bf16 N(0,1) data maxes out ~5.
__global__ void k_detect(const unsigned short* __restrict__ x, int* __restrict__ flag) {
    __shared__ float red[256];
    float m = 0.0f;
    for (int i = threadIdx.x; i < 8192; i += 256) {
        float f = __uint_as_float(((uint32_t)x[i]) << 16);
        f = fabsf(f);
        if (isnan(f)) f = 3.0e38f;
        m = fmaxf(m, f);
    }
    red[threadIdx.x] = m;
    __syncthreads();
    for (int off = 128; off > 0; off >>= 1) {
        if (threadIdx.x < off) red[threadIdx.x] = fmaxf(red[threadIdx.x], red[threadIdx.x + off]);
        __syncthreads();
    }
    if (threadIdx.x == 0) flag[0] = (red[0] < 1.0e6f) ? 1 : 0;
}

// ---------------- converts ----------------
__global__ void k_convert(const void* __restrict__ src, float* __restrict__ dst,
                          int n, const int* __restrict__ flag) {
    const int f = *flag;
    for (int i = blockIdx.x * blockDim.x + threadIdx.x; i < n; i += gridDim.x * blockDim.x) {
        float v;
        if (f) v = bf2f(((const unsigned short*)src)[i]);
        else   v = ((const float*)src)[i];
        dst[i] = v;
    }
}

// in: [S][384][128] row-major  ->  out: [S][128][384]  (k-major for GEMM B-tiles)
__global__ void k_convert_T(const void* __restrict__ src, float* __restrict__ dst,
                            const int* __restrict__ flag) {
    const int total = NSETS * 384 * 128;
    const int f = *flag;
    for (int i = blockIdx.x * blockDim.x + threadIdx.x; i < total; i += gridDim.x * blockDim.x) {
        int s = i / (384 * 128);
        int rem = i - s * 384 * 128;
        int k = rem / 384;
        int r = rem - k * 384;
        int si = s * 384 * 128 + r * 128 + k;
        float v;
        if (f) v = bf2f(((const unsigned short*)src)[si]);
        else   v = ((const float*)src)[si];
        dst[i] = v;
    }
}

// ---------------- CSR build ----------------
__global__ void k_deg(const int* __restrict__ ei, const int* __restrict__ attr,
                      int* __restrict__ cnt) {
    int e = blockIdx.x * 256 + threadIdx.x;
    if (e < N_EDGES) {
        int t = attr[e];
        int d = ei[N_EDGES + e];
        atomicAdd(&cnt[t * N_NODES + d], 1);
    }
}

__global__ void k_scan1(const int* __restrict__ cnt, int* __restrict__ rp,
                        int* __restrict__ part, int n) {
    __shared__ int buf[1024];
    int gid = blockIdx.x * 1024 + threadIdx.x;
    int v = (gid < n) ? cnt[gid] : 0;
    buf[threadIdx.x] = v;
    __syncthreads();
    for (int off = 1; off < 1024; off <<= 1) {
        int t = (threadIdx.x >= off) ? buf[threadIdx.x - off] : 0;
        __syncthreads();
        buf[threadIdx.x] += t;
        __syncthreads();
    }
    if (gid < n) rp[gid] = buf[threadIdx.x] - v;   // block-local exclusive
    if (threadIdx.x == 1023) part[blockIdx.x] = buf[1023];
}

__global__ void k_scan2(int* __restrict__ part, int nb) {
    __shared__ int buf[1024];
    int v = (threadIdx.x < nb) ? part[threadIdx.x] : 0;
    buf[threadIdx.x] = v;
    __syncthreads();
    for (int off = 1; off < 1024; off <<= 1) {
        int t = (threadIdx.x >= off) ? buf[threadIdx.x - off] : 0;
        __syncthreads();
        buf[threadIdx.x] += t;
        __syncthreads();
    }
    if (threadIdx.x < nb) part[threadIdx.x] = buf[threadIdx.x] - v;  // exclusive
}

__global__ void k_scan3(int* __restrict__ rp, int* __restrict__ cursor,
                        const int* __restrict__ part, int n) {
    int gid = blockIdx.x * 1024 + threadIdx.x;
    if (gid < n) {
        int v = rp[gid] + part[blockIdx.x];
        rp[gid] = v;
        cursor[gid] = v;
    }
    if (gid == 0) rp[n] = N_EDGES;
}

__global__ void k_fill(const int* __restrict__ ei, const int* __restrict__ attr,
                       int* __restrict__ cursor, int* __restrict__ col) {
    int e = blockIdx.x * 256 + threadIdx.x;
    if (e < N_EDGES) {
        int t = attr[e];
        int d = ei[N_EDGES + e];
        int s = ei[e];
        int pos = atomicAdd(&cursor[t * N_NODES + d], 1);
        col[pos] = s;
    }
}

// ---------------- fused GGC step ----------------
// Per 64-node block:
//   A0: g = mean-gather(hin via CSR) -> sA[k][n] (fp32);  hin tile -> sH[k][n] (bf16)
//   A1: agg = g @ W  (in regs), A2: write agg^T back over sA
//   B : 3 gate GEMMs (r,z,n) of [64,128]x[128,128] x2 (wih, whh), gates in regs
//   epilogue: GRU combine, mode-dependent writes (h / acc= / acc+= / x=(acc+h)/3)
__global__ void __launch_bounds__(256, 2)
k_gru(const float* __restrict__ hin, float* __restrict__ hout,
      float* __restrict__ accb, float* __restrict__ xout,
      const float* __restrict__ Wsi,
      const float* __restrict__ wihT_s, const float* __restrict__ whhT_s,
      const float* __restrict__ bih_s, const float* __restrict__ bhh_s,
      const int* __restrict__ rp_s, const int* __restrict__ colarr,
      int mode)
{
    __shared__ float sA[128][64];            // 32 KB : g^T, then agg^T
    __shared__ unsigned short sH[128][64];   // 16 KB : h^T (bf16)
    __shared__ float sW0[16][128];           //  8 KB
    __shared__ float sW1[16][128];           //  8 KB

    const int tid = threadIdx.x;
    const int tx8 = (tid & 15) * 8;
    const int ty4 = (tid >> 4) * 4;
    const int n0 = blockIdx.x * 64;

    // ---- Phase A0 ----
    {
        const int n = tid >> 2;     // 0..63
        const int p = tid & 3;      // feature quarter (32 floats)
        const int gn = n0 + n;
        float4 a[8], own[8];
#pragma unroll
        for (int j = 0; j < 8; ++j) { a[j] = make_float4(0,0,0,0); own[j] = make_float4(0,0,0,0); }
        if (gn < N_NODES) {
            const float4* hp = (const float4*)(hin + (size_t)gn * DIM + p * 32);
#pragma unroll
            for (int j = 0; j < 8; ++j) own[j] = hp[j];
            const int beg = rp_s[gn], end = rp_s[gn + 1];
            int dg = end - beg; if (dg < 1) dg = 1;
            const float inv = 1.0f / (float)dg;
            for (int e = beg; e < end; ++e) {
                const int c = colarr[e];
                const float4* mp = (const float4*)(hin + (size_t)c * DIM + p * 32);
#pragma unroll
                for (int j = 0; j < 8; ++j) {
                    float4 v = mp[j];
                    a[j].x += v.x; a[j].y += v.y; a[j].z += v.z; a[j].w += v.w;
                }
            }
#pragma unroll
            for (int j = 0; j < 8; ++j) { a[j].x *= inv; a[j].y *= inv; a[j].z *= inv; a[j].w *= inv; }
        }
#pragma unroll
        for (int j = 0; j < 8; ++j) {
            const int fb = p * 32 + j * 4;
            sA[fb + 0][n] = a[j].x; sA[fb + 1][n] = a[j].y;
            sA[fb + 2][n] = a[j].z; sA[fb + 3][n] = a[j].w;
            sH[fb + 0][n] = f2bf(own[j].x); sH[fb + 1][n] = f2bf(own[j].y);
            sH[fb + 2][n] = f2bf(own[j].z); sH[fb + 3][n] = f2bf(own[j].w);
        }
    }
    __syncthreads();

    // ---- Phase A1: agg = g @ W ----
    float acc0[4][8];
#pragma unroll
    for (int i = 0; i < 4; ++i)
#pragma unroll
        for (int j = 0; j < 8; ++j) acc0[i][j] = 0.0f;

    for (int kc = 0; kc < 8; ++kc) {
        {
            const int rr = tid >> 4;
            const int cc = (tid & 15) * 8;
            const float* g = Wsi + (size_t)(kc * 16 + rr) * DIM + cc;
            *(float4*)&sW0[rr][cc]     = *(const float4*)g;
            *(float4*)&sW0[rr][cc + 4] = *(const float4*)(g + 4);
        }
        __syncthreads();
#pragma unroll
        for (int kk = 0; kk < 16; ++kk) {
            const int k = kc * 16 + kk;
            const float4 av = *(const float4*)&sA[k][ty4];
            const float4 b0 = *(const float4*)&sW0[kk][tx8];
            const float4 b1 = *(const float4*)&sW0[kk][tx8 + 4];
            const float aa[4] = {av.x, av.y, av.z, av.w};
            const float bb[8] = {b0.x, b0.y, b0.z, b0.w, b1.x, b1.y, b1.z, b1.w};
#pragma unroll
            for (int i = 0; i < 4; ++i)
#pragma unroll
                for (int j = 0; j < 8; ++j)
                    acc0[i][j] = fmaf(aa[i], bb[j], acc0[i][j]);
        }
        __syncthreads();
    }
    // ---- Phase A2: agg^T over sA ----
#pragma unroll
    for (int i = 0; i < 4; ++i)
#pragma unroll
        for (int j = 0; j < 8; ++j)
            sA[tx8 + j][ty4 + i] = acc0[i][j];
    __syncthreads();

    // ---- Phase B: gate GEMMs ----
    auto gate_gemm = [&](int goff, float (&acci)[4][8], float (&acch)[4][8]) {
#pragma unroll
        for (int i = 0; i < 4; ++i)
#pragma unroll
            for (int j = 0; j < 8; ++j) { acci[i][j] = 0.0f; acch[i][j] = 0.0f; }
        for (int kc = 0; kc < 8; ++kc) {
            {
                const int rr = tid >> 4;
                const int cc = (tid & 15) * 8;
                const float* g0 = wihT_s + (size_t)(kc * 16 + rr) * 384 + goff + cc;
                const float* g1 = whhT_s + (size_t)(kc * 16 + rr) * 384 + goff + cc;
                *(float4*)&sW0[rr][cc]     = *(const float4*)g0;
                *(float4*)&sW0[rr][cc + 4] = *(const float4*)(g0 + 4);
                *(float4*)&sW1[rr][cc]     = *(const float4*)g1;
                *(float4*)&sW1[rr][cc + 4] = *(const float4*)(g1 + 4);
            }
            __syncthreads();
#pragma unroll
            for (int kk = 0; kk < 16; ++kk) {
                const int k = kc * 16 + kk;
                const float4 av = *(const float4*)&sA[k][ty4];
                const uint2  hu = *(const uint2*)&sH[k][ty4];
                const float aa[4] = {av.x, av.y, av.z, av.w};
                const float ah[4] = {
                    __uint_as_float(hu.x << 16), __uint_as_float(hu.x & 0xFFFF0000u),
                    __uint_as_float(hu.y << 16), __uint_as_float(hu.y & 0xFFFF0000u)
                };
                const float4 c0 = *(const float4*)&sW0[kk][tx8];
                const float4 c1 = *(const float4*)&sW0[kk][tx8 + 4];
                const float4 d0 = *(const float4*)&sW1[kk][tx8];
                const float4 d1 = *(const float4*)&sW1[kk][tx8 + 4];
                const float bi[8] = {c0.x, c0.y, c0.z, c0.w, c1.x, c1.y, c1.z, c1.w};
                const float bh[8] = {d0.x, d0.y, d0.z, d0.w, d1.x, d1.y, d1.z, d1.w};
#pragma unroll
                for (int i = 0; i < 4; ++i)
#pragma unroll
                    for (int j = 0; j < 8; ++j) {
                        acci[i][j] = fmaf(aa[i], bi[j], acci[i][j]);
                        acch[i][j] = fmaf(ah[i], bh[j], acch[i][j]);
                    }
            }
            __syncthreads();
        }
    };

    float r_[4][8], z_[4][8];
    float acci[4][8], acch[4][8];

    // gate r (goff 0)
    gate_gemm(0, acci, acch);
    {
        const float4 b0 = *(const float4*)(bih_s + tx8);
        const float4 b1 = *(const float4*)(bih_s + tx8 + 4);
        const float4 c0 = *(const float4*)(bhh_s + tx8);
        const float4 c1 = *(const float4*)(bhh_s + tx8 + 4);
        const float bi[8] = {b0.x, b0.y, b0.z, b0.w, b1.x, b1.y, b1.z, b1.w};
        const float bh[8] = {c0.x, c0.y, c0.z, c0.w, c1.x, c1.y, c1.z, c1.w};
#pragma unroll
        for (int i = 0; i < 4; ++i)
#pragma unroll
            for (int j = 0; j < 8; ++j)
                r_[i][j] = sigmoidf_(acci[i][j] + bi[j] + acch[i][j] + bh[j]);
    }
    // gate z (goff 128)
    gate_gemm(128, acci, acch);
    {
        const float4 b0 = *(const float4*)(bih_s + 128 + tx8);
        const float4 b1 = *(const float4*)(bih_s + 128 + tx8 + 4);
        const float4 c0 = *(const float4*)(bhh_s + 128 + tx8);
        const float4 c1 = *(const float4*)(bhh_s + 128 + tx8 + 4);
        const float bi[8] = {b0.x, b0.y, b0.z, b0.w, b1.x, b1.y, b1.z, b1.w};
        const float bh[8] = {c0.x, c0.y, c0.z, c0.w, c1.x, c1.y, c1.z, c1.w};
#pragma unroll
        for (int i = 0; i < 4; ++i)
#pragma unroll
            for (int j = 0; j < 8; ++j)
                z_[i][j] = sigmoidf_(acci[i][j] + bi[j] + acch[i][j] + bh[j]);
    }
    // gate n (goff 256) + epilogue
    gate_gemm(256, acci, acch);
    {
        const float4 b0 = *(const float4*)(bih_s + 256 + tx8);
        const float4 b1 = *(const float4*)(bih_s + 256 + tx8 + 4);
        const float4 c0 = *(const float4*)(bhh_s + 256 + tx8);
        const float4 c1 = *(const float4*)(bhh_s + 256 + tx8 + 4);
        const float bi[8] = {b0.x, b0.y, b0.z, b0.w, b1.x, b1.y, b1.z, b1.w};
        const float bh[8] = {c0.x, c0.y, c0.z, c0.w, c1.x, c1.y, c1.z, c1.w};
#pragma unroll
        for (int i = 0; i < 4; ++i) {
            const int gn = n0 + ty4 + i;
            if (gn >= N_NODES) continue;
            const size_t base = (size_t)gn * DIM + tx8;
            const float4 h0 = *(const float4*)(hin + base);
            const float4 h1 = *(const float4*)(hin + base + 4);
            const float hv[8] = {h0.x, h0.y, h0.z, h0.w, h1.x, h1.y, h1.z, h1.w};
            float out[8];
#pragma unroll
            for (int j = 0; j < 8; ++j) {
                const float nn = tanhf(acci[i][j] + bi[j] + r_[i][j] * (acch[i][j] + bh[j]));
                out[j] = (1.0f - z_[i][j]) * nn + z_[i][j] * hv[j];
            }
            float4 o0 = make_float4(out[0], out[1], out[2], out[3]);
            float4 o1 = make_float4(out[4], out[5], out[6], out[7]);
            if (mode == 0) {
                *(float4*)(hout + base) = o0;
                *(float4*)(hout + base + 4) = o1;
            } else if (mode == 1) {
                *(float4*)(accb + base) = o0;
                *(float4*)(accb + base + 4) = o1;
            } else if (mode == 2) {
                float4 p0 = *(const float4*)(accb + base);
                float4 p1 = *(const float4*)(accb + base + 4);
                p0.x += o0.x; p0.y += o0.y; p0.z += o0.z; p0.w += o0.w;
                p1.x += o1.x; p1.y += o1.y; p1.z += o1.z; p1.w += o1.w;
                *(float4*)(accb + base) = p0;
                *(float4*)(accb + base + 4) = p1;
            } else {
                const float third = (1.0f / 3.0f);
                float4 p0 = *(const float4*)(accb + base);
                float4 p1 = *(const float4*)(accb + base + 4);
                p0.x = (p0.x + o0.x) * third; p0.y = (p0.y + o0.y) * third;
                p0.z = (p0.z + o0.z) * third; p0.w = (p0.w + o0.w) * third;
                p1.x = (p1.x + o1.x) * third; p1.y = (p1.y + o1.y) * third;
                p1.z = (p1.z + o1.z) * third; p1.w = (p1.w + o1.w) * third;
                *(float4*)(xout + base) = p0;
                *(float4*)(xout + base + 4) = p1;
            }
        }
    }
}

// ---------------- pooling ----------------
__global__ void k_pool(const float* __restrict__ xf, const int* __restrict__ batch,
                       float* __restrict__ pooled, int* __restrict__ gcnt) {
    const int tid = threadIdx.x;
    const int f = tid & 127;
    const int half = tid >> 7;
    const int nstart = blockIdx.x * 64 + half * 32;
    float accv = 0.0f;
    int curg = -1, cnt = 0;
    for (int t = 0; t < 32; ++t) {
        const int n = nstart + t;
        if (n >= N_NODES) break;
        const int g = batch[n];
        if (g != curg) {
            if (curg >= 0) {
                atomicAdd(&pooled[curg * DIM + f], accv);
                if (f == 0) atomicAdd(&gcnt[curg], cnt);
            }
            curg = g; accv = 0.0f; cnt = 0;
        }
        accv += xf[(size_t)n * DIM + f];
        cnt++;
    }
    if (curg >= 0) {
        atomicAdd(&pooled[curg * DIM + f], accv);
        if (f == 0) atomicAdd(&gcnt[curg], cnt);
    }
}

// ---------------- MLP head ----------------
__global__ void k_head(const float* __restrict__ pooled, const int* __restrict__ gcnt,
                       const float* __restrict__ ptf,
                       const float* __restrict__ fc1w, const float* __restrict__ fc1b,
                       const float* __restrict__ fc2w, const float* __restrict__ fc2b,
                       const float* __restrict__ fclw, const float* __restrict__ fclb,
                       void* __restrict__ out, const int* __restrict__ flag) {
    __shared__ float xh[64 * 129];
    __shared__ float h1[64 * 80];
    const int tid = threadIdx.x;
    for (int i = tid; i < 64 * 128; i += 256) {
        const int g = i >> 7;
        int c = gcnt[g]; if (c < 1) c = 1;
        xh[g * 129 + (i & 127)] = pooled[i] / (float)c;
    }
    for (int g = tid; g < 64; g += 256) xh[g * 129 + 128] = ptf[g];
    __syncthreads();
    for (int i = tid; i < 64 * 80; i += 256) {
        const int g = i / 80, c = i - g * 80;
        float s = fc1b[c];
        const float* xr = &xh[g * 129];
        const float* wr = &fc1w[c * 129];
        for (int k = 0; k < 129; ++k) s += xr[k] * wr[k];
        h1[i] = (s > 0.0f) ? s : 0.01f * s;
    }
    __syncthreads();
    float* h2 = xh;  // reuse (xh dead after fc1)
    for (int i = tid; i < 64 * 80; i += 256) {
        const int g = i / 80, c = i - g * 80;
        float s = fc2b[c];
        const float* hr = &h1[g * 80];
        const float* wr = &fc2w[c * 80];
        for (int k = 0; k < 80; ++k) s += hr[k] * wr[k];
        h2[i] = (s > 0.0f) ? s : 0.01f * s;
    }
    __syncthreads();
    for (int i = tid; i < 128; i += 256) {
        const int g = i >> 1, c = i & 1;
        float s = fclb[c];
        const float* hr = &h2[g * 80];
        const float* wr = &fclw[c * 80];
        for (int k = 0; k < 80; ++k) s += hr[k] * wr[k];
        if (*flag) ((unsigned short*)out)[i] = f2bf(s);
        else       ((float*)out)[i] = s;
    }
}

// ---------------- launcher ----------------
extern "C" void kernel_launch(void* const* d_in, const int* in_sizes, int n_in,
                              void* d_out, int out_size, void* d_ws, size_t ws_size,
                              hipStream_t stream) {
    if (n_in < 16) return;
    const void* x_in    = d_in[0];
    const int*  ei      = (const int*)d_in[1];
    const int*  attr    = (const int*)d_in[2];
    const int*  batch   = (const int*)d_in[3];
    const void* pt_in   = d_in[4];
    const void* W_in    = d_in[5];
    const void* wih_in  = d_in[6];
    const void* whh_in  = d_in[7];
    const void* bih_in  = d_in[8];
    const void* bhh_in  = d_in[9];
    const void* fc1w_in = d_in[10];
    const void* fc1b_in = d_in[11];
    const void* fc2w_in = d_in[12];
    const void* fc2b_in = d_in[13];
    const void* fclw_in = d_in[14];
    const void* fclb_in = d_in[15];

    char* ws = (char*)d_ws;
    size_t o = 0;
    auto alloc = [&](size_t b) { size_t r = o; o += (b + 255) & ~(size_t)255; return r; };

    const size_t o_flag   = alloc(4);
    const size_t o_xf     = alloc((size_t)N_NODES * DIM * 4);
    const size_t o_hbuf   = alloc((size_t)N_NODES * DIM * 4);
    const size_t o_accb   = alloc((size_t)N_NODES * DIM * 4);
    const size_t o_Wf     = alloc((size_t)NSETS * NLAYERS * DIM * DIM * 4);
    const size_t o_wihT   = alloc((size_t)NSETS * DIM * 384 * 4);
    const size_t o_whhT   = alloc((size_t)NSETS * DIM * 384 * 4);
    const size_t o_bih    = alloc((size_t)NSETS * 384 * 4);
    const size_t o_bhh    = alloc((size_t)NSETS * 384 * 4);
    const size_t o_fc1w   = alloc(10320 * 4);
    const size_t o_fc1b   = alloc(80 * 4);
    const size_t o_fc2w   = alloc(6400 * 4);
    const size_t o_fc2b   = alloc(80 * 4);
    const size_t o_fclw   = alloc(160 * 4);
    const size_t o_fclb   = alloc(2 * 4);
    const size_t o_ptf    = alloc(64 * 4);
    const size_t o_cnt    = alloc((size_t)3 * N_NODES * 4);
    const size_t o_cursor = alloc((size_t)3 * N_NODES * 4);
    const size_t o_rp     = alloc(((size_t)3 * N_NODES + 1) * 4);
    const size_t o_col    = alloc((size_t)N_EDGES * 4);
    const int    nb_scan  = (3 * N_NODES + 1023) / 1024;
    const size_t o_part   = alloc((size_t)nb_scan * 4);
    const size_t o_pooled = alloc((size_t)NGRAPH * DIM * 4);
    const size_t o_gcnt   = alloc((size_t)NGRAPH * 4);

    if (ws_size < o) {
        fprintf(stderr, "GGNN kernel: workspace too small: need %zu, have %zu\n", o, ws_size);
        return;
    }

    int*   flag   = (int*)(ws + o_flag);
    float* xf     = (float*)(ws + o_xf);
    float* hbuf   = (float*)(ws + o_hbuf);
    float* accb   = (float*)(ws + o_accb);
    float* Wf     = (float*)(ws + o_Wf);
    float* wihT   = (float*)(ws + o_wihT);
    float* whhT   = (float*)(ws + o_whhT);
    float* bihf   = (float*)(ws + o_bih);
    float* bhhf   = (float*)(ws + o_bhh);
    float* fc1wf  = (float*)(ws + o_fc1w);
    float* fc1bf  = (float*)(ws + o_fc1b);
    float* fc2wf  = (float*)(ws + o_fc2w);
    float* fc2bf  = (float*)(ws + o_fc2b);
    float* fclwf  = (float*)(ws + o_fclw);
    float* fclbf  = (float*)(ws + o_fclb);
    float* ptf    = (float*)(ws + o_ptf);
    int*   cnt    = (int*)(ws + o_cnt);
    int*   cursor = (int*)(ws + o_cursor);
    int*   rp     = (int*)(ws + o_rp);
    int*   col    = (int*)(ws + o_col);
    int*   part   = (int*)(ws + o_part);
    float* pooled = (float*)(ws + o_pooled);
    int*   gcnt   = (int*)(ws + o_gcnt);

    hipMemsetAsync(cnt, 0, (size_t)3 * N_NODES * 4, stream);
    hipMemsetAsync(pooled, 0, (o_gcnt - o_pooled) + (size_t)NGRAPH * 4, stream);

    k_detect<<<1, 256, 0, stream>>>((const unsigned short*)x_in, flag);

    // converts
    {
        int n = N_NODES * DIM;
        int nb = (n + 2047) / 2048;
        k_convert<<<nb, 256, 0, stream>>>(x_in, xf, n, flag);
    }
    k_convert<<<(NSETS * NLAYERS * DIM * DIM + 255) / 256, 256, 0, stream>>>(W_in, Wf, NSETS * NLAYERS * DIM * DIM, flag);
    k_convert_T<<<(NSETS * 384 * 128 + 255) / 256, 256, 0, stream>>>(wih_in, wihT, flag);
    k_convert_T<<<(NSETS * 384 * 128 + 255) / 256, 256, 0, stream>>>(whh_in, whhT, flag);
    k_convert<<<(NSETS * 384 + 255) / 256, 256, 0, stream>>>(bih_in, bihf, NSETS * 384, flag);
    k_convert<<<(NSETS * 384 + 255) / 256, 256, 0, stream>>>(bhh_in, bhhf, NSETS * 384, flag);
    k_convert<<<(10320 + 255) / 256, 256, 0, stream>>>(fc1w_in, fc1wf, 10320, flag);
    k_convert<<<1, 256, 0, stream>>>(fc1b_in, fc1bf, 80, flag);
    k_convert<<<(6400 + 255) / 256, 256, 0, stream>>>(fc2w_in, fc2wf, 6400, flag);
    k_convert<<<1, 256, 0, stream>>>(fc2b_in, fc2bf, 80, flag);
    k_convert<<<1, 256, 0, stream>>>(fclw_in, fclwf, 160, flag);
    k_convert<<<1, 256, 0, stream>>>(fclb_in, fclbf, 2, flag);
    k_convert<<<1, 256, 0, stream>>>(pt_in, ptf, 64, flag);

    // CSR build
    k_deg<<<(N_EDGES + 255) / 256, 256, 0, stream>>>(ei, attr, cnt);
    k_scan1<<<nb_scan, 1024, 0, stream>>>(cnt, rp, part, 3 * N_NODES);
    k_scan2<<<1, 1024, 0, stream>>>(part, nb_scan);
    k_scan3<<<nb_scan, 1024, 0, stream>>>(rp, cursor, part, 3 * N_NODES);
    k_fill<<<(N_EDGES + 255) / 256, 256, 0, stream>>>(ei, attr, cursor, col);

    // GGC steps
    const int NB_GRU = (N_NODES + 63) / 64;
    for (int pass = 0; pass < NPASS; ++pass) {
        for (int s = 0; s < NSETS; ++s) {
            for (int i = 0; i < NLAYERS; ++i) {
                const float* hin = (i == 0) ? xf : hbuf;
                int mode;
                if (i < NLAYERS - 1) mode = 0;
                else mode = (s == 0) ? 1 : ((s == 1) ? 2 : 3);
                k_gru<<<NB_GRU, 256, 0, stream>>>(
                    hin, hbuf, accb, xf,
                    Wf + (size_t)(s * NLAYERS + i) * DIM * DIM,
                    wihT + (size_t)s * DIM * 384,
                    whhT + (size_t)s * DIM * 384,
                    bihf + (size_t)s * 384,
                    bhhf + (size_t)s * 384,
                    rp + (size_t)s * N_NODES,
                    col, mode);
            }
        }
    }

    // pooling + head
    k_pool<<<NB_GRU, 256, 0, stream>>>(xf, batch, pooled, gcnt);
    k_head<<<1, 256, 0, stream>>>(pooled, gcnt, ptf, fc1wf, fc1bf, fc2wf, fc2bf,
                                  fclwf, fclbf, d_out, flag);
}

// Round 2
// 2975.015 us; speedup vs baseline: 5.0586x; 5.0586x over previous
//
#include <hip/hip_runtime.h>
#include <cstdio>
#include <cstdint>

#define N_NODES 100000
#define N_EDGES 600000
#define DIM     128
#define NSETS   3
#define NLAYERS 2
#define NGRAPH  64
#define NPASS   2
#define SP      136   // LDS row stride in shorts (272 B: 16B-aligned rows, 4-bank row skew)

typedef __bf16 bf16x8 __attribute__((ext_vector_type(8)));
typedef float  f32x4  __attribute__((ext_vector_type(4)));
typedef unsigned short u16;

static __device__ __forceinline__ float bf2f(u16 u) {
    return __uint_as_float(((uint32_t)u) << 16);
}
static __device__ __forceinline__ u16 f2bf(float f) {
    uint32_t u = __float_as_uint(f);
    uint32_t r = (u + 0x7FFFu + ((u >> 16) & 1u)) >> 16;
    return (u16)r;
}
static __device__ __forceinline__ uint32_t packbf(float lo, float hi) {
    return (uint32_t)f2bf(lo) | ((uint32_t)f2bf(hi) << 16);
}
static __device__ __forceinline__ float sigmoidf_(float x) {
    return 1.0f / (1.0f + __expf(-x));
}

// ---------------- dtype detection ----------------
__global__ void k_detect(const u16* __restrict__ x, int* __restrict__ flag) {
    __shared__ float red[256];
    float m = 0.0f;
    for (int i = threadIdx.x; i < 8192; i += 256) {
        float f = __uint_as_float(((uint32_t)x[i]) << 16);
        f = fabsf(f);
        if (isnan(f)) f = 3.0e38f;
        m = fmaxf(m, f);
    }
    red[threadIdx.x] = m;
    __syncthreads();
    for (int off = 128; off > 0; off >>= 1) {
        if (threadIdx.x < off) red[threadIdx.x] = fmaxf(red[threadIdx.x], red[threadIdx.x + off]);
        __syncthreads();
    }
    if (threadIdx.x == 0) flag[0] = (red[0] < 1.0e6f) ? 1 : 0;
}

// ---------------- converts ----------------
__global__ void k_convert(const void* __restrict__ src, float* __restrict__ dst,
                          int n, const int* __restrict__ flag) {
    const int f = *flag;
    for (int i = blockIdx.x * blockDim.x + threadIdx.x; i < n; i += gridDim.x * blockDim.x) {
        float v;
        if (f) v = bf2f(((const u16*)src)[i]);
        else   v = ((const float*)src)[i];
        dst[i] = v;
    }
}

// W: [S*L][k 128][n 128] -> Wt hi/lo: [S*L][n 128][k 128] (bf16 split)
__global__ void k_prep_W(const void* __restrict__ src, u16* __restrict__ hi,
                         u16* __restrict__ lo, const int* __restrict__ flag) {
    const int total = NSETS * NLAYERS * DIM * DIM;
    const int f = *flag;
    for (int i = blockIdx.x * blockDim.x + threadIdx.x; i < total; i += gridDim.x * blockDim.x) {
        int sl = i / (DIM * DIM);
        int rem = i - sl * DIM * DIM;
        int n = rem / DIM;
        int k = rem - n * DIM;
        int si = sl * DIM * DIM + k * DIM + n;
        float v;
        if (f) v = bf2f(((const u16*)src)[si]);
        else   v = ((const float*)src)[si];
        u16 h = f2bf(v);
        hi[i] = h;
        lo[i] = f2bf(v - bf2f(h));
    }
}

// wih/whh: [S][384][128] -> hi/lo bf16 same layout ([col][k], k contiguous = B-frag ready)
__global__ void k_prep_G(const void* __restrict__ src, u16* __restrict__ hi,
                         u16* __restrict__ lo, const int* __restrict__ flag) {
    const int total = NSETS * 384 * DIM;
    const int f = *flag;
    for (int i = blockIdx.x * blockDim.x + threadIdx.x; i < total; i += gridDim.x * blockDim.x) {
        float v;
        if (f) v = bf2f(((const u16*)src)[i]);
        else   v = ((const float*)src)[i];
        u16 h = f2bf(v);
        hi[i] = h;
        lo[i] = f2bf(v - bf2f(h));
    }
}

// ---------------- CSR build ----------------
__global__ void k_deg(const int* __restrict__ ei, const int* __restrict__ attr,
                      int* __restrict__ cnt) {
    int e = blockIdx.x * 256 + threadIdx.x;
    if (e < N_EDGES) {
        int t = attr[e];
        int d = ei[N_EDGES + e];
        atomicAdd(&cnt[t * N_NODES + d], 1);
    }
}

__global__ void k_scan1(const int* __restrict__ cnt, int* __restrict__ rp,
                        int* __restrict__ part, int n) {
    __shared__ int buf[1024];
    int gid = blockIdx.x * 1024 + threadIdx.x;
    int v = (gid < n) ? cnt[gid] : 0;
    buf[threadIdx.x] = v;
    __syncthreads();
    for (int off = 1; off < 1024; off <<= 1) {
        int t = (threadIdx.x >= off) ? buf[threadIdx.x - off] : 0;
        __syncthreads();
        buf[threadIdx.x] += t;
        __syncthreads();
    }
    if (gid < n) rp[gid] = buf[threadIdx.x] - v;
    if (threadIdx.x == 1023) part[blockIdx.x] = buf[1023];
}

__global__ void k_scan2(int* __restrict__ part, int nb) {
    __shared__ int buf[1024];
    int v = (threadIdx.x < nb) ? part[threadIdx.x] : 0;
    buf[threadIdx.x] = v;
    __syncthreads();
    for (int off = 1; off < 1024; off <<= 1) {
        int t = (threadIdx.x >= off) ? buf[threadIdx.x - off] : 0;
        __syncthreads();
        buf[threadIdx.x] += t;
        __syncthreads();
    }
    if (threadIdx.x < nb) part[threadIdx.x] = buf[threadIdx.x] - v;
}

__global__ void k_scan3(int* __restrict__ rp, int* __restrict__ cursor,
                        const int* __restrict__ part, int n) {
    int gid = blockIdx.x * 1024 + threadIdx.x;
    if (gid < n) {
        int v = rp[gid] + part[blockIdx.x];
        rp[gid] = v;
        cursor[gid] = v;
    }
    if (gid == 0) rp[n] = N_EDGES;
}

__global__ void k_fill(const int* __restrict__ ei, const int* __restrict__ attr,
                       int* __restrict__ cursor, int* __restrict__ col) {
    int e = blockIdx.x * 256 + threadIdx.x;
    if (e < N_EDGES) {
        int t = attr[e];
        int d = ei[N_EDGES + e];
        int s = ei[e];
        int pos = atomicAdd(&cursor[t * N_NODES + d], 1);
        col[pos] = s;
    }
}

// ---------------- fused GGC step (MFMA) ----------------
// 64 nodes/block, 4 waves. Wave w owns output cols [w*32, w*32+32).
// A0: gather mean -> sG (bf16), own h -> sH (bf16). lane=node => conflict-free uint4 LDS stores.
// A1: agg = g @ W (MFMA, B = Wt hi/lo from global), round-trip agg through sG.
// rz: C = agg@wih^T + h@whh^T for r,z cols (K-concat via two mfma chains into one acc).
// n : i_n, h_n separate accs; epilogue: GRU combine with fp32 h from global.
__global__ void __launch_bounds__(256, 3)
k_gru(const float* __restrict__ hin, float* __restrict__ hout,
      float* __restrict__ accb, float* __restrict__ xout,
      const u16* __restrict__ Wt_hi, const u16* __restrict__ Wt_lo,
      const u16* __restrict__ wih_hi, const u16* __restrict__ wih_lo,
      const u16* __restrict__ whh_hi, const u16* __restrict__ whh_lo,
      const float* __restrict__ bih_s, const float* __restrict__ bhh_s,
      const int* __restrict__ rp_s, const int* __restrict__ colarr,
      int mode)
{
    __shared__ u16 sG[64 * SP];   // 17408 B : g, then agg
    __shared__ u16 sH[64 * SP];   // 17408 B : h

    const int tid  = threadIdx.x;
    const int lane = tid & 63;
    const int wv   = tid >> 6;
    const int l15  = lane & 15;
    const int quad = lane >> 4;
    const int n0   = blockIdx.x * 64;
    const int colbase = wv * 32;

    // bias preload: [gate r/z/n][nt]
    float b_i[3][2], b_h[3][2];
#pragma unroll
    for (int g = 0; g < 3; ++g)
#pragma unroll
        for (int nt = 0; nt < 2; ++nt) {
            const int c = g * 128 + colbase + nt * 16 + l15;
            b_i[g][nt] = bih_s[c];
            b_h[g][nt] = bhh_s[c];
        }

    // ---- Phase A0: gather ----
    {
        const int n = tid & 63;        // node (one per lane -> conflict-free stores)
        const int p = tid >> 6;        // 32-float feature quarter
        const int gn = n0 + n;
        float a[32];
#pragma unroll
        for (int j = 0; j < 32; ++j) a[j] = 0.0f;
        float hv[32];
#pragma unroll
        for (int j = 0; j < 32; ++j) hv[j] = 0.0f;
        if (gn < N_NODES) {
            const float4* hp = (const float4*)(hin + (size_t)gn * DIM + p * 32);
#pragma unroll
            for (int j = 0; j < 8; ++j) {
                float4 v = hp[j];
                hv[4 * j] = v.x; hv[4 * j + 1] = v.y; hv[4 * j + 2] = v.z; hv[4 * j + 3] = v.w;
            }
            const int beg = rp_s[gn], end = rp_s[gn + 1];
            int dg = end - beg; if (dg < 1) dg = 1;
            const float inv = 1.0f / (float)dg;
            for (int e = beg; e < end; ++e) {
                const int c = colarr[e];
                const float4* mp = (const float4*)(hin + (size_t)c * DIM + p * 32);
#pragma unroll
                for (int j = 0; j < 8; ++j) {
                    float4 v = mp[j];
                    a[4 * j] += v.x; a[4 * j + 1] += v.y; a[4 * j + 2] += v.z; a[4 * j + 3] += v.w;
                }
            }
#pragma unroll
            for (int j = 0; j < 32; ++j) a[j] *= inv;
        }
        uint4* gd = (uint4*)&sG[n * SP + p * 32];
        uint4* hd = (uint4*)&sH[n * SP + p * 32];
#pragma unroll
        for (int j = 0; j < 4; ++j) {
            gd[j] = make_uint4(packbf(a[8 * j], a[8 * j + 1]), packbf(a[8 * j + 2], a[8 * j + 3]),
                               packbf(a[8 * j + 4], a[8 * j + 5]), packbf(a[8 * j + 6], a[8 * j + 7]));
            hd[j] = make_uint4(packbf(hv[8 * j], hv[8 * j + 1]), packbf(hv[8 * j + 2], hv[8 * j + 3]),
                               packbf(hv[8 * j + 4], hv[8 * j + 5]), packbf(hv[8 * j + 6], hv[8 * j + 7]));
        }
    }
    __syncthreads();

    // ---- Phase A1: agg = g @ W ----
    f32x4 accA[4][2];
#pragma unroll
    for (int mt = 0; mt < 4; ++mt)
#pragma unroll
        for (int nt = 0; nt < 2; ++nt) accA[mt][nt] = (f32x4){0.f, 0.f, 0.f, 0.f};

#pragma unroll
    for (int ks = 0; ks < 4; ++ks) {
        const int k0 = ks * 32;
        bf16x8 ag[4];
#pragma unroll
        for (int mt = 0; mt < 4; ++mt)
            ag[mt] = *(const bf16x8*)&sG[(mt * 16 + l15) * SP + k0 + quad * 8];
#pragma unroll
        for (int nt = 0; nt < 2; ++nt) {
            const size_t boff = (size_t)(colbase + nt * 16 + l15) * 128 + k0 + quad * 8;
            bf16x8 bhi = *(const bf16x8*)(Wt_hi + boff);
            bf16x8 blo = *(const bf16x8*)(Wt_lo + boff);
#pragma unroll
            for (int mt = 0; mt < 4; ++mt) {
                accA[mt][nt] = __builtin_amdgcn_mfma_f32_16x16x32_bf16(ag[mt], bhi, accA[mt][nt], 0, 0, 0);
                accA[mt][nt] = __builtin_amdgcn_mfma_f32_16x16x32_bf16(ag[mt], blo, accA[mt][nt], 0, 0, 0);
            }
        }
    }
    __syncthreads();   // all waves done reading g
#pragma unroll
    for (int mt = 0; mt < 4; ++mt)
#pragma unroll
        for (int nt = 0; nt < 2; ++nt) {
            const int c = colbase + nt * 16 + l15;
#pragma unroll
            for (int r = 0; r < 4; ++r)
                sG[(mt * 16 + quad * 4 + r) * SP + c] = f2bf(accA[mt][nt][r]);
        }
    __syncthreads();

    // ---- Phase rz ----
    f32x4 acc_rz[4][4];   // [mt][ct]: ct 0,1 = r cols; 2,3 = z cols
#pragma unroll
    for (int mt = 0; mt < 4; ++mt)
#pragma unroll
        for (int ct = 0; ct < 4; ++ct) acc_rz[mt][ct] = (f32x4){0.f, 0.f, 0.f, 0.f};

#pragma unroll
    for (int ks = 0; ks < 4; ++ks) {
        const int k0 = ks * 32;
        bf16x8 ag[4], ah[4];
#pragma unroll
        for (int mt = 0; mt < 4; ++mt) {
            ag[mt] = *(const bf16x8*)&sG[(mt * 16 + l15) * SP + k0 + quad * 8];
            ah[mt] = *(const bf16x8*)&sH[(mt * 16 + l15) * SP + k0 + quad * 8];
        }
#pragma unroll
        for (int ct = 0; ct < 4; ++ct) {
            const int col0 = (ct < 2) ? (colbase + ct * 16) : (128 + colbase + (ct - 2) * 16);
            const size_t boff = (size_t)(col0 + l15) * 128 + k0 + quad * 8;
            bf16x8 bi_h = *(const bf16x8*)(wih_hi + boff);
            bf16x8 bi_l = *(const bf16x8*)(wih_lo + boff);
            bf16x8 bh_h = *(const bf16x8*)(whh_hi + boff);
            bf16x8 bh_l = *(const bf16x8*)(whh_lo + boff);
#pragma unroll
            for (int mt = 0; mt < 4; ++mt) {
                f32x4 acc = acc_rz[mt][ct];
                acc = __builtin_amdgcn_mfma_f32_16x16x32_bf16(ag[mt], bi_h, acc, 0, 0, 0);
                acc = __builtin_amdgcn_mfma_f32_16x16x32_bf16(ag[mt], bi_l, acc, 0, 0, 0);
                acc = __builtin_amdgcn_mfma_f32_16x16x32_bf16(ah[mt], bh_h, acc, 0, 0, 0);
                acc = __builtin_amdgcn_mfma_f32_16x16x32_bf16(ah[mt], bh_l, acc, 0, 0, 0);
                acc_rz[mt][ct] = acc;
            }
        }
    }
    // rz epilogue: pack r (low16) and z (high16) as bf16
    uint32_t rzp[4][2][4];
#pragma unroll
    for (int mt = 0; mt < 4; ++mt)
#pragma unroll
        for (int nt = 0; nt < 2; ++nt) {
            const float br = b_i[0][nt] + b_h[0][nt];
            const float bz = b_i[1][nt] + b_h[1][nt];
#pragma unroll
            for (int r = 0; r < 4; ++r) {
                const float rr = sigmoidf_(acc_rz[mt][nt][r] + br);
                const float zz = sigmoidf_(acc_rz[mt][nt + 2][r] + bz);
                rzp[mt][nt][r] = packbf(rr, zz);
            }
        }

    // ---- Phase n ----
    f32x4 acc_i[4][2], acc_h[4][2];
#pragma unroll
    for (int mt = 0; mt < 4; ++mt)
#pragma unroll
        for (int nt = 0; nt < 2; ++nt) {
            acc_i[mt][nt] = (f32x4){0.f, 0.f, 0.f, 0.f};
            acc_h[mt][nt] = (f32x4){0.f, 0.f, 0.f, 0.f};
        }
#pragma unroll
    for (int ks = 0; ks < 4; ++ks) {
        const int k0 = ks * 32;
        bf16x8 ag[4], ah[4];
#pragma unroll
        for (int mt = 0; mt < 4; ++mt) {
            ag[mt] = *(const bf16x8*)&sG[(mt * 16 + l15) * SP + k0 + quad * 8];
            ah[mt] = *(const bf16x8*)&sH[(mt * 16 + l15) * SP + k0 + quad * 8];
        }
#pragma unroll
        for (int nt = 0; nt < 2; ++nt) {
            const size_t boff = (size_t)(256 + colbase + nt * 16 + l15) * 128 + k0 + quad * 8;
            bf16x8 bi_h = *(const bf16x8*)(wih_hi + boff);
            bf16x8 bi_l = *(const bf16x8*)(wih_lo + boff);
            bf16x8 bh_h = *(const bf16x8*)(whh_hi + boff);
            bf16x8 bh_l = *(const bf16x8*)(whh_lo + boff);
#pragma unroll
            for (int mt = 0; mt < 4; ++mt) {
                acc_i[mt][nt] = __builtin_amdgcn_mfma_f32_16x16x32_bf16(ag[mt], bi_h, acc_i[mt][nt], 0, 0, 0);
                acc_i[mt][nt] = __builtin_amdgcn_mfma_f32_16x16x32_bf16(ag[mt], bi_l, acc_i[mt][nt], 0, 0, 0);
                acc_h[mt][nt] = __builtin_amdgcn_mfma_f32_16x16x32_bf16(ah[mt], bh_h, acc_h[mt][nt], 0, 0, 0);
                acc_h[mt][nt] = __builtin_amdgcn_mfma_f32_16x16x32_bf16(ah[mt], bh_l, acc_h[mt][nt], 0, 0, 0);
            }
        }
    }

    // ---- epilogue: GRU combine + mode writes ----
#pragma unroll
    for (int mt = 0; mt < 4; ++mt)
#pragma unroll
        for (int nt = 0; nt < 2; ++nt) {
            const int c = colbase + nt * 16 + l15;
#pragma unroll
            for (int r = 0; r < 4; ++r) {
                const int gn = n0 + mt * 16 + quad * 4 + r;
                if (gn >= N_NODES) continue;
                const size_t idx = (size_t)gn * DIM + c;
                const float i_n = acc_i[mt][nt][r] + b_i[2][nt];
                const float h_n = acc_h[mt][nt][r] + b_h[2][nt];
                const uint32_t p = rzp[mt][nt][r];
                const float rr = bf2f((u16)(p & 0xFFFFu));
                const float zz = bf2f((u16)(p >> 16));
                const float nn = tanhf(i_n + rr * h_n);
                const float hv = hin[idx];
                const float out = (1.0f - zz) * nn + zz * hv;
                if (mode == 0)      hout[idx] = out;
                else if (mode == 1) accb[idx] = out;
                else if (mode == 2) accb[idx] += out;
                else                xout[idx] = (accb[idx] + out) * (1.0f / 3.0f);
            }
        }
}

// ---------------- pooling ----------------
__global__ void k_pool(const float* __restrict__ xf, const int* __restrict__ batch,
                       float* __restrict__ pooled, int* __restrict__ gcnt) {
    const int tid = threadIdx.x;
    const int f = tid & 127;
    const int half = tid >> 7;
    const int nstart = blockIdx.x * 64 + half * 32;
    float accv = 0.0f;
    int curg = -1, cnt = 0;
    for (int t = 0; t < 32; ++t) {
        const int n = nstart + t;
        if (n >= N_NODES) break;
        const int g = batch[n];
        if (g != curg) {
            if (curg >= 0) {
                atomicAdd(&pooled[curg * DIM + f], accv);
                if (f == 0) atomicAdd(&gcnt[curg], cnt);
            }
            curg = g; accv = 0.0f; cnt = 0;
        }
        accv += xf[(size_t)n * DIM + f];
        cnt++;
    }
    if (curg >= 0) {
        atomicAdd(&pooled[curg * DIM + f], accv);
        if (f == 0) atomicAdd(&gcnt[curg], cnt);
    }
}

// ---------------- MLP head ----------------
__global__ void k_head(const float* __restrict__ pooled, const int* __restrict__ gcnt,
                       const float* __restrict__ ptf,
                       const float* __restrict__ fc1w, const float* __restrict__ fc1b,
                       const float* __restrict__ fc2w, const float* __restrict__ fc2b,
                       const float* __restrict__ fclw, const float* __restrict__ fclb,
                       void* __restrict__ out, const int* __restrict__ flag) {
    __shared__ float xh[64 * 129];
    __shared__ float h1[64 * 80];
    const int tid = threadIdx.x;
    for (int i = tid; i < 64 * 128; i += 256) {
        const int g = i >> 7;
        int c = gcnt[g]; if (c < 1) c = 1;
        xh[g * 129 + (i & 127)] = pooled[i] / (float)c;
    }
    for (int g = tid; g < 64; g += 256) xh[g * 129 + 128] = ptf[g];
    __syncthreads();
    for (int i = tid; i < 64 * 80; i += 256) {
        const int g = i / 80, c = i - g * 80;
        float s = fc1b[c];
        const float* xr = &xh[g * 129];
        const float* wr = &fc1w[c * 129];
        for (int k = 0; k < 129; ++k) s += xr[k] * wr[k];
        h1[i] = (s > 0.0f) ? s : 0.01f * s;
    }
    __syncthreads();
    float* h2 = xh;
    for (int i = tid; i < 64 * 80; i += 256) {
        const int g = i / 80, c = i - g * 80;
        float s = fc2b[c];
        const float* hr = &h1[g * 80];
        const float* wr = &fc2w[c * 80];
        for (int k = 0; k < 80; ++k) s += hr[k] * wr[k];
        h2[i] = (s > 0.0f) ? s : 0.01f * s;
    }
    __syncthreads();
    for (int i = tid; i < 128; i += 256) {
        const int g = i >> 1, c = i & 1;
        float s = fclb[c];
        const float* hr = &h2[g * 80];
        const float* wr = &fclw[c * 80];
        for (int k = 0; k < 80; ++k) s += hr[k] * wr[k];
        if (*flag) ((u16*)out)[i] = f2bf(s);
        else       ((float*)out)[i] = s;
    }
}

// ---------------- launcher ----------------
extern "C" void kernel_launch(void* const* d_in, const int* in_sizes, int n_in,
                              void* d_out, int out_size, void* d_ws, size_t ws_size,
                              hipStream_t stream) {
    if (n_in < 16) return;
    const void* x_in    = d_in[0];
    const int*  ei      = (const int*)d_in[1];
    const int*  attr    = (const int*)d_in[2];
    const int*  batch   = (const int*)d_in[3];
    const void* pt_in   = d_in[4];
    const void* W_in    = d_in[5];
    const void* wih_in  = d_in[6];
    const void* whh_in  = d_in[7];
    const void* bih_in  = d_in[8];
    const void* bhh_in  = d_in[9];
    const void* fc1w_in = d_in[10];
    const void* fc1b_in = d_in[11];
    const void* fc2w_in = d_in[12];
    const void* fc2b_in = d_in[13];
    const void* fclw_in = d_in[14];
    const void* fclb_in = d_in[15];

    char* ws = (char*)d_ws;
    size_t o = 0;
    auto alloc = [&](size_t b) { size_t r = o; o += (b + 255) & ~(size_t)255; return r; };

    const size_t o_flag   = alloc(4);
    const size_t o_xf     = alloc((size_t)N_NODES * DIM * 4);
    const size_t o_hbuf   = alloc((size_t)N_NODES * DIM * 4);
    const size_t o_accb   = alloc((size_t)N_NODES * DIM * 4);
    const size_t o_Wt_hi  = alloc((size_t)NSETS * NLAYERS * DIM * DIM * 2);
    const size_t o_Wt_lo  = alloc((size_t)NSETS * NLAYERS * DIM * DIM * 2);
    const size_t o_wih_hi = alloc((size_t)NSETS * 384 * DIM * 2);
    const size_t o_wih_lo = alloc((size_t)NSETS * 384 * DIM * 2);
    const size_t o_whh_hi = alloc((size_t)NSETS * 384 * DIM * 2);
    const size_t o_whh_lo = alloc((size_t)NSETS * 384 * DIM * 2);
    const size_t o_bih    = alloc((size_t)NSETS * 384 * 4);
    const size_t o_bhh    = alloc((size_t)NSETS * 384 * 4);
    const size_t o_fc1w   = alloc(10320 * 4);
    const size_t o_fc1b   = alloc(80 * 4);
    const size_t o_fc2w   = alloc(6400 * 4);
    const size_t o_fc2b   = alloc(80 * 4);
    const size_t o_fclw   = alloc(160 * 4);
    const size_t o_fclb   = alloc(2 * 4);
    const size_t o_ptf    = alloc(64 * 4);
    const size_t o_cnt    = alloc((size_t)3 * N_NODES * 4);
    const size_t o_cursor = alloc((size_t)3 * N_NODES * 4);
    const size_t o_rp     = alloc(((size_t)3 * N_NODES + 1) * 4);
    const size_t o_col    = alloc((size_t)N_EDGES * 4);
    const int    nb_scan  = (3 * N_NODES + 1023) / 1024;
    const size_t o_part   = alloc((size_t)nb_scan * 4);
    const size_t o_pooled = alloc((size_t)NGRAPH * DIM * 4);
    const size_t o_gcnt   = alloc((size_t)NGRAPH * 4);

    if (ws_size < o) {
        fprintf(stderr, "GGNN kernel: workspace too small: need %zu, have %zu\n", o, ws_size);
        return;
    }

    int*   flag   = (int*)(ws + o_flag);
    float* xf     = (float*)(ws + o_xf);
    float* hbuf   = (float*)(ws + o_hbuf);
    float* accb   = (float*)(ws + o_accb);
    u16*   Wt_hi  = (u16*)(ws + o_Wt_hi);
    u16*   Wt_lo  = (u16*)(ws + o_Wt_lo);
    u16*   wih_hi = (u16*)(ws + o_wih_hi);
    u16*   wih_lo = (u16*)(ws + o_wih_lo);
    u16*   whh_hi = (u16*)(ws + o_whh_hi);
    u16*   whh_lo = (u16*)(ws + o_whh_lo);
    float* bihf   = (float*)(ws + o_bih);
    float* bhhf   = (float*)(ws + o_bhh);
    float* fc1wf  = (float*)(ws + o_fc1w);
    float* fc1bf  = (float*)(ws + o_fc1b);
    float* fc2wf  = (float*)(ws + o_fc2w);
    float* fc2bf  = (float*)(ws + o_fc2b);
    float* fclwf  = (float*)(ws + o_fclw);
    float* fclbf  = (float*)(ws + o_fclb);
    float* ptf    = (float*)(ws + o_ptf);
    int*   cnt    = (int*)(ws + o_cnt);
    int*   cursor = (int*)(ws + o_cursor);
    int*   rp     = (int*)(ws + o_rp);
    int*   col    = (int*)(ws + o_col);
    int*   part   = (int*)(ws + o_part);
    float* pooled = (float*)(ws + o_pooled);
    int*   gcnt   = (int*)(ws + o_gcnt);

    hipMemsetAsync(cnt, 0, (size_t)3 * N_NODES * 4, stream);
    hipMemsetAsync(pooled, 0, (o_gcnt - o_pooled) + (size_t)NGRAPH * 4, stream);

    k_detect<<<1, 256, 0, stream>>>((const u16*)x_in, flag);

    // converts + weight prep
    {
        int n = N_NODES * DIM;
        int nb = (n + 2047) / 2048;
        k_convert<<<nb, 256, 0, stream>>>(x_in, xf, n, flag);
    }
    k_prep_W<<<(NSETS * NLAYERS * DIM * DIM + 255) / 256, 256, 0, stream>>>(W_in, Wt_hi, Wt_lo, flag);
    k_prep_G<<<(NSETS * 384 * DIM + 255) / 256, 256, 0, stream>>>(wih_in, wih_hi, wih_lo, flag);
    k_prep_G<<<(NSETS * 384 * DIM + 255) / 256, 256, 0, stream>>>(whh_in, whh_hi, whh_lo, flag);
    k_convert<<<(NSETS * 384 + 255) / 256, 256, 0, stream>>>(bih_in, bihf, NSETS * 384, flag);
    k_convert<<<(NSETS * 384 + 255) / 256, 256, 0, stream>>>(bhh_in, bhhf, NSETS * 384, flag);
    k_convert<<<(10320 + 255) / 256, 256, 0, stream>>>(fc1w_in, fc1wf, 10320, flag);
    k_convert<<<1, 256, 0, stream>>>(fc1b_in, fc1bf, 80, flag);
    k_convert<<<(6400 + 255) / 256, 256, 0, stream>>>(fc2w_in, fc2wf, 6400, flag);
    k_convert<<<1, 256, 0, stream>>>(fc2b_in, fc2bf, 80, flag);
    k_convert<<<1, 256, 0, stream>>>(fclw_in, fclwf, 160, flag);
    k_convert<<<1, 256, 0, stream>>>(fclb_in, fclbf, 2, flag);
    k_convert<<<1, 256, 0, stream>>>(pt_in, ptf, 64, flag);

    // CSR build
    k_deg<<<(N_EDGES + 255) / 256, 256, 0, stream>>>(ei, attr, cnt);
    k_scan1<<<nb_scan, 1024, 0, stream>>>(cnt, rp, part, 3 * N_NODES);
    k_scan2<<<1, 1024, 0, stream>>>(part, nb_scan);
    k_scan3<<<nb_scan, 1024, 0, stream>>>(rp, cursor, part, 3 * N_NODES);
    k_fill<<<(N_EDGES + 255) / 256, 256, 0, stream>>>(ei, attr, cursor, col);

    // GGC steps
    const int NB_GRU = (N_NODES + 63) / 64;
    for (int pass = 0; pass < NPASS; ++pass) {
        for (int s = 0; s < NSETS; ++s) {
            for (int i = 0; i < NLAYERS; ++i) {
                const float* hin = (i == 0) ? xf : hbuf;
                int mode;
                if (i < NLAYERS - 1) mode = 0;
                else mode = (s == 0) ? 1 : ((s == 1) ? 2 : 3);
                k_gru<<<NB_GRU, 256, 0, stream>>>(
                    hin, hbuf, accb, xf,
                    Wt_hi + (size_t)(s * NLAYERS + i) * DIM * DIM,
                    Wt_lo + (size_t)(s * NLAYERS + i) * DIM * DIM,
                    wih_hi + (size_t)s * 384 * DIM,
                    wih_lo + (size_t)s * 384 * DIM,
                    whh_hi + (size_t)s * 384 * DIM,
                    whh_lo + (size_t)s * 384 * DIM,
                    bihf + (size_t)s * 384,
                    bhhf + (size_t)s * 384,
                    rp + (size_t)s * N_NODES,
                    col, mode);
            }
        }
    }

    // pooling + head
    k_pool<<<NB_GRU, 256, 0, stream>>>(xf, batch, pooled, gcnt);
    k_head<<<1, 256, 0, stream>>>(pooled, gcnt, ptf, fc1wf, fc1bf, fc2wf, fc2bf,
                                  fclwf, fclbf, d_out, flag);
}

// Round 3
// 2597.448 us; speedup vs baseline: 5.7939x; 1.1454x over previous
//
#include <hip/hip_runtime.h>
#include <cstdio>
#include <cstdint>

#define N_NODES 100000
#define N_EDGES 600000
#define DIM     128
#define NSETS   3
#define NLAYERS 2
#define NGRAPH  64
#define NPASS   2
#define SP      136   // LDS row stride in shorts (272 B: 16B-aligned rows)

typedef __bf16 bf16x8 __attribute__((ext_vector_type(8)));
typedef float  f32x4  __attribute__((ext_vector_type(4)));
typedef unsigned short u16;

static __device__ __forceinline__ float bf2f(u16 u) {
    return __uint_as_float(((uint32_t)u) << 16);
}
static __device__ __forceinline__ u16 f2bf(float f) {
    uint32_t u = __float_as_uint(f);
    uint32_t r = (u + 0x7FFFu + ((u >> 16) & 1u)) >> 16;
    return (u16)r;
}
static __device__ __forceinline__ uint32_t packbf(float lo, float hi) {
    return (uint32_t)f2bf(lo) | ((uint32_t)f2bf(hi) << 16);
}
static __device__ __forceinline__ void unpack_add(uint32_t u, float& a0, float& a1) {
    a0 += __uint_as_float(u << 16);
    a1 += __uint_as_float(u & 0xFFFF0000u);
}
static __device__ __forceinline__ float sigmoidf_(float x) {
    return 1.0f / (1.0f + __expf(-x));
}

// ---------------- dtype detection ----------------
__global__ void k_detect(const u16* __restrict__ x, int* __restrict__ flag) {
    __shared__ float red[256];
    float m = 0.0f;
    for (int i = threadIdx.x; i < 8192; i += 256) {
        float f = __uint_as_float(((uint32_t)x[i]) << 16);
        f = fabsf(f);
        if (isnan(f)) f = 3.0e38f;
        m = fmaxf(m, f);
    }
    red[threadIdx.x] = m;
    __syncthreads();
    for (int off = 128; off > 0; off >>= 1) {
        if (threadIdx.x < off) red[threadIdx.x] = fmaxf(red[threadIdx.x], red[threadIdx.x + off]);
        __syncthreads();
    }
    if (threadIdx.x == 0) flag[0] = (red[0] < 1.0e6f) ? 1 : 0;
}

// ---------------- converts ----------------
__global__ void k_convert(const void* __restrict__ src, float* __restrict__ dst,
                          int n, const int* __restrict__ flag) {
    const int f = *flag;
    for (int i = blockIdx.x * blockDim.x + threadIdx.x; i < n; i += gridDim.x * blockDim.x) {
        float v;
        if (f) v = bf2f(((const u16*)src)[i]);
        else   v = ((const float*)src)[i];
        dst[i] = v;
    }
}

__global__ void k_to_bf(const void* __restrict__ src, u16* __restrict__ dst,
                        int n, const int* __restrict__ flag) {
    const int f = *flag;
    for (int i = blockIdx.x * blockDim.x + threadIdx.x; i < n; i += gridDim.x * blockDim.x) {
        if (f) dst[i] = ((const u16*)src)[i];
        else   dst[i] = f2bf(((const float*)src)[i]);
    }
}

// W: [S*L][k 128][n 128] -> Wt hi/lo: [S*L][n 128][k 128] (bf16 split)
__global__ void k_prep_W(const void* __restrict__ src, u16* __restrict__ hi,
                         u16* __restrict__ lo, const int* __restrict__ flag) {
    const int total = NSETS * NLAYERS * DIM * DIM;
    const int f = *flag;
    for (int i = blockIdx.x * blockDim.x + threadIdx.x; i < total; i += gridDim.x * blockDim.x) {
        int sl = i / (DIM * DIM);
        int rem = i - sl * DIM * DIM;
        int n = rem / DIM;
        int k = rem - n * DIM;
        int si = sl * DIM * DIM + k * DIM + n;
        float v;
        if (f) v = bf2f(((const u16*)src)[si]);
        else   v = ((const float*)src)[si];
        u16 h = f2bf(v);
        hi[i] = h;
        lo[i] = f2bf(v - bf2f(h));
    }
}

// wih/whh: [S][384][128] -> hi/lo bf16 same layout ([col][k], k contiguous)
__global__ void k_prep_G(const void* __restrict__ src, u16* __restrict__ hi,
                         u16* __restrict__ lo, const int* __restrict__ flag) {
    const int total = NSETS * 384 * DIM;
    const int f = *flag;
    for (int i = blockIdx.x * blockDim.x + threadIdx.x; i < total; i += gridDim.x * blockDim.x) {
        float v;
        if (f) v = bf2f(((const u16*)src)[i]);
        else   v = ((const float*)src)[i];
        u16 h = f2bf(v);
        hi[i] = h;
        lo[i] = f2bf(v - bf2f(h));
    }
}

// ---------------- CSR build ----------------
__global__ void k_deg(const int* __restrict__ ei, const int* __restrict__ attr,
                      int* __restrict__ cnt) {
    int e = blockIdx.x * 256 + threadIdx.x;
    if (e < N_EDGES) {
        int t = attr[e];
        int d = ei[N_EDGES + e];
        atomicAdd(&cnt[t * N_NODES + d], 1);
    }
}

__global__ void k_scan1(const int* __restrict__ cnt, int* __restrict__ rp,
                        int* __restrict__ part, int n) {
    __shared__ int buf[1024];
    int gid = blockIdx.x * 1024 + threadIdx.x;
    int v = (gid < n) ? cnt[gid] : 0;
    buf[threadIdx.x] = v;
    __syncthreads();
    for (int off = 1; off < 1024; off <<= 1) {
        int t = (threadIdx.x >= off) ? buf[threadIdx.x - off] : 0;
        __syncthreads();
        buf[threadIdx.x] += t;
        __syncthreads();
    }
    if (gid < n) rp[gid] = buf[threadIdx.x] - v;
    if (threadIdx.x == 1023) part[blockIdx.x] = buf[1023];
}

__global__ void k_scan2(int* __restrict__ part, int nb) {
    __shared__ int buf[1024];
    int v = (threadIdx.x < nb) ? part[threadIdx.x] : 0;
    buf[threadIdx.x] = v;
    __syncthreads();
    for (int off = 1; off < 1024; off <<= 1) {
        int t = (threadIdx.x >= off) ? buf[threadIdx.x - off] : 0;
        __syncthreads();
        buf[threadIdx.x] += t;
        __syncthreads();
    }
    if (threadIdx.x < nb) part[threadIdx.x] = buf[threadIdx.x] - v;
}

__global__ void k_scan3(int* __restrict__ rp, int* __restrict__ cursor,
                        const int* __restrict__ part, int n) {
    int gid = blockIdx.x * 1024 + threadIdx.x;
    if (gid < n) {
        int v = rp[gid] + part[blockIdx.x];
        rp[gid] = v;
        cursor[gid] = v;
    }
    if (gid == 0) rp[n] = N_EDGES;
}

__global__ void k_fill(const int* __restrict__ ei, const int* __restrict__ attr,
                       int* __restrict__ cursor, int* __restrict__ col) {
    int e = blockIdx.x * 256 + threadIdx.x;
    if (e < N_EDGES) {
        int t = attr[e];
        int d = ei[N_EDGES + e];
        int s = ei[e];
        int pos = atomicAdd(&cursor[t * N_NODES + d], 1);
        col[pos] = s;
    }
}

// ---------------- fused GGC layer (3 edge sets, MFMA) ----------------
// 64 nodes/block, 4 waves; wave owns cols [wv*32, wv*32+32).
// layer==0: hin = x (staged once), writes h0,h1,h2 (bf16, LDS-transposed coalesced).
// layer==1: hin = h_s per set, accumulates 3-set GRU outputs in regs,
//           writes x = sum/3 (bf16) at the end. No accb round-trip.
__global__ void __launch_bounds__(256, 2)
k_step(const u16* __restrict__ xin, u16* __restrict__ h0, u16* __restrict__ h1,
       u16* __restrict__ h2, u16* __restrict__ xout,
       const u16* __restrict__ Wt_hi, const u16* __restrict__ Wt_lo,
       const u16* __restrict__ wih_hi, const u16* __restrict__ wih_lo,
       const u16* __restrict__ whh_hi, const u16* __restrict__ whh_lo,
       const float* __restrict__ bih, const float* __restrict__ bhh,
       const int* __restrict__ rp, const int* __restrict__ colarr, int layer)
{
    __shared__ u16 sG[64 * SP];   // gathered mean -> agg -> (layer0) out staging
    __shared__ u16 sH[64 * SP];   // own h (bf16)

    const int tid  = threadIdx.x;
    const int lane = tid & 63;
    const int wv   = tid >> 6;
    const int l15  = lane & 15;
    const int quad = lane >> 4;
    const int n0   = blockIdx.x * 64;
    const int colbase = wv * 32;
    const int sn   = tid & 63;    // staging: node within block
    const int sp4  = tid >> 6;    // staging: 32-col quarter (64 B bf16)
    const int sgn  = n0 + sn;

    u16* const hbufs[3] = {h0, h1, h2};

    // layer-0: own x staged once, valid across all 3 sets
    if (layer == 0) {
        uint4 v0 = {0,0,0,0}, v1 = {0,0,0,0}, v2 = {0,0,0,0}, v3 = {0,0,0,0};
        if (sgn < N_NODES) {
            const uint4* s = (const uint4*)(xin + (size_t)sgn * DIM + sp4 * 32);
            v0 = s[0]; v1 = s[1]; v2 = s[2]; v3 = s[3];
        }
        uint4* d = (uint4*)&sH[sn * SP + sp4 * 32];
        d[0] = v0; d[1] = v1; d[2] = v2; d[3] = v3;
    }

    f32x4 sum[4][2];
#pragma unroll
    for (int mt = 0; mt < 4; ++mt)
#pragma unroll
        for (int nt = 0; nt < 2; ++nt) sum[mt][nt] = (f32x4){0.f, 0.f, 0.f, 0.f};

    for (int s = 0; s < NSETS; ++s) {
        const u16* src = (layer == 0) ? xin : hbufs[s];
        const u16* Ws_hi  = Wt_hi + (size_t)(s * NLAYERS + layer) * DIM * DIM;
        const u16* Ws_lo  = Wt_lo + (size_t)(s * NLAYERS + layer) * DIM * DIM;
        const u16* wi_hi  = wih_hi + (size_t)s * 384 * DIM;
        const u16* wi_lo  = wih_lo + (size_t)s * 384 * DIM;
        const u16* wh_hi  = whh_hi + (size_t)s * 384 * DIM;
        const u16* wh_lo  = whh_lo + (size_t)s * 384 * DIM;
        const float* bi_s = bih + (size_t)s * 384;
        const float* bh_s = bhh + (size_t)s * 384;
        const int* rp_s   = rp + (size_t)s * N_NODES;

        __syncthreads();   // prior-iter readers of sG/sH done

        if (layer == 1) {  // stage own h_s
            uint4 v0 = {0,0,0,0}, v1 = {0,0,0,0}, v2 = {0,0,0,0}, v3 = {0,0,0,0};
            if (sgn < N_NODES) {
                const uint4* sp = (const uint4*)(src + (size_t)sgn * DIM + sp4 * 32);
                v0 = sp[0]; v1 = sp[1]; v2 = sp[2]; v3 = sp[3];
            }
            uint4* d = (uint4*)&sH[sn * SP + sp4 * 32];
            d[0] = v0; d[1] = v1; d[2] = v2; d[3] = v3;
        }

        // ---- gather mean -> sG ----
        {
            float a[32];
#pragma unroll
            for (int j = 0; j < 32; ++j) a[j] = 0.0f;
            if (sgn < N_NODES) {
                const int beg = rp_s[sgn], end = rp_s[sgn + 1];
                int dg = end - beg; if (dg < 1) dg = 1;
                const float inv = 1.0f / (float)dg;
                for (int e = beg; e < end; ++e) {
                    const int c = colarr[e];
                    const uint4* mp = (const uint4*)(src + (size_t)c * DIM + sp4 * 32);
#pragma unroll
                    for (int j = 0; j < 4; ++j) {
                        uint4 v = mp[j];
                        unpack_add(v.x, a[8 * j + 0], a[8 * j + 1]);
                        unpack_add(v.y, a[8 * j + 2], a[8 * j + 3]);
                        unpack_add(v.z, a[8 * j + 4], a[8 * j + 5]);
                        unpack_add(v.w, a[8 * j + 6], a[8 * j + 7]);
                    }
                }
#pragma unroll
                for (int j = 0; j < 32; ++j) a[j] *= inv;
            }
            uint4* gd = (uint4*)&sG[sn * SP + sp4 * 32];
#pragma unroll
            for (int j = 0; j < 4; ++j)
                gd[j] = make_uint4(packbf(a[8 * j], a[8 * j + 1]), packbf(a[8 * j + 2], a[8 * j + 3]),
                                   packbf(a[8 * j + 4], a[8 * j + 5]), packbf(a[8 * j + 6], a[8 * j + 7]));
        }
        __syncthreads();

        // biases for this wave's columns
        float bi_r[2], bh_r[2], bi_z[2], bh_z[2], bi_n[2], bh_n[2];
#pragma unroll
        for (int nt = 0; nt < 2; ++nt) {
            const int c = colbase + nt * 16 + l15;
            bi_r[nt] = bi_s[c];        bh_r[nt] = bh_s[c];
            bi_z[nt] = bi_s[128 + c];  bh_z[nt] = bh_s[128 + c];
            bi_n[nt] = bi_s[256 + c];  bh_n[nt] = bh_s[256 + c];
        }

        // ---- A1: agg = g @ W ----
        f32x4 accA[4][2];
#pragma unroll
        for (int mt = 0; mt < 4; ++mt)
#pragma unroll
            for (int nt = 0; nt < 2; ++nt) accA[mt][nt] = (f32x4){0.f, 0.f, 0.f, 0.f};
#pragma unroll
        for (int ks = 0; ks < 4; ++ks) {
            const int k0 = ks * 32;
            bf16x8 ag[4];
#pragma unroll
            for (int mt = 0; mt < 4; ++mt)
                ag[mt] = *(const bf16x8*)&sG[(mt * 16 + l15) * SP + k0 + quad * 8];
#pragma unroll
            for (int nt = 0; nt < 2; ++nt) {
                const size_t boff = (size_t)(colbase + nt * 16 + l15) * 128 + k0 + quad * 8;
                bf16x8 bhi = *(const bf16x8*)(Ws_hi + boff);
                bf16x8 blo = *(const bf16x8*)(Ws_lo + boff);
#pragma unroll
                for (int mt = 0; mt < 4; ++mt) {
                    accA[mt][nt] = __builtin_amdgcn_mfma_f32_16x16x32_bf16(ag[mt], bhi, accA[mt][nt], 0, 0, 0);
                    accA[mt][nt] = __builtin_amdgcn_mfma_f32_16x16x32_bf16(ag[mt], blo, accA[mt][nt], 0, 0, 0);
                }
            }
        }
        __syncthreads();   // all waves done reading g
#pragma unroll
        for (int mt = 0; mt < 4; ++mt)
#pragma unroll
            for (int nt = 0; nt < 2; ++nt) {
                const int c = colbase + nt * 16 + l15;
#pragma unroll
                for (int r = 0; r < 4; ++r)
                    sG[(mt * 16 + quad * 4 + r) * SP + c] = f2bf(accA[mt][nt][r]);
            }
        __syncthreads();

        // ---- gates: r, z (packed bf16), then n ----
        uint32_t rz[4][2][4];   // low16 = r, high16 = z (bf16)

        // r gate (cols 0..127 of the 384)
        {
            f32x4 acc[4][2];
#pragma unroll
            for (int mt = 0; mt < 4; ++mt)
#pragma unroll
                for (int nt = 0; nt < 2; ++nt) acc[mt][nt] = (f32x4){0.f, 0.f, 0.f, 0.f};
#pragma unroll
            for (int ks = 0; ks < 4; ++ks) {
                const int k0 = ks * 32;
                bf16x8 ag[4], ah[4];
#pragma unroll
                for (int mt = 0; mt < 4; ++mt) {
                    ag[mt] = *(const bf16x8*)&sG[(mt * 16 + l15) * SP + k0 + quad * 8];
                    ah[mt] = *(const bf16x8*)&sH[(mt * 16 + l15) * SP + k0 + quad * 8];
                }
#pragma unroll
                for (int nt = 0; nt < 2; ++nt) {
                    const size_t boff = (size_t)(colbase + nt * 16 + l15) * 128 + k0 + quad * 8;
                    bf16x8 bih8 = *(const bf16x8*)(wi_hi + boff);
                    bf16x8 bil8 = *(const bf16x8*)(wi_lo + boff);
                    bf16x8 bhh8 = *(const bf16x8*)(wh_hi + boff);
                    bf16x8 bhl8 = *(const bf16x8*)(wh_lo + boff);
#pragma unroll
                    for (int mt = 0; mt < 4; ++mt) {
                        f32x4 a2 = acc[mt][nt];
                        a2 = __builtin_amdgcn_mfma_f32_16x16x32_bf16(ag[mt], bih8, a2, 0, 0, 0);
                        a2 = __builtin_amdgcn_mfma_f32_16x16x32_bf16(ag[mt], bil8, a2, 0, 0, 0);
                        a2 = __builtin_amdgcn_mfma_f32_16x16x32_bf16(ah[mt], bhh8, a2, 0, 0, 0);
                        a2 = __builtin_amdgcn_mfma_f32_16x16x32_bf16(ah[mt], bhl8, a2, 0, 0, 0);
                        acc[mt][nt] = a2;
                    }
                }
            }
#pragma unroll
            for (int mt = 0; mt < 4; ++mt)
#pragma unroll
                for (int nt = 0; nt < 2; ++nt) {
                    const float bb = bi_r[nt] + bh_r[nt];
#pragma unroll
                    for (int r = 0; r < 4; ++r)
                        rz[mt][nt][r] = (uint32_t)f2bf(sigmoidf_(acc[mt][nt][r] + bb));
                }
        }
        // z gate (cols 128..255)
        {
            f32x4 acc[4][2];
#pragma unroll
            for (int mt = 0; mt < 4; ++mt)
#pragma unroll
                for (int nt = 0; nt < 2; ++nt) acc[mt][nt] = (f32x4){0.f, 0.f, 0.f, 0.f};
#pragma unroll
            for (int ks = 0; ks < 4; ++ks) {
                const int k0 = ks * 32;
                bf16x8 ag[4], ah[4];
#pragma unroll
                for (int mt = 0; mt < 4; ++mt) {
                    ag[mt] = *(const bf16x8*)&sG[(mt * 16 + l15) * SP + k0 + quad * 8];
                    ah[mt] = *(const bf16x8*)&sH[(mt * 16 + l15) * SP + k0 + quad * 8];
                }
#pragma unroll
                for (int nt = 0; nt < 2; ++nt) {
                    const size_t boff = (size_t)(128 + colbase + nt * 16 + l15) * 128 + k0 + quad * 8;
                    bf16x8 bih8 = *(const bf16x8*)(wi_hi + boff);
                    bf16x8 bil8 = *(const bf16x8*)(wi_lo + boff);
                    bf16x8 bhh8 = *(const bf16x8*)(wh_hi + boff);
                    bf16x8 bhl8 = *(const bf16x8*)(wh_lo + boff);
#pragma unroll
                    for (int mt = 0; mt < 4; ++mt) {
                        f32x4 a2 = acc[mt][nt];
                        a2 = __builtin_amdgcn_mfma_f32_16x16x32_bf16(ag[mt], bih8, a2, 0, 0, 0);
                        a2 = __builtin_amdgcn_mfma_f32_16x16x32_bf16(ag[mt], bil8, a2, 0, 0, 0);
                        a2 = __builtin_amdgcn_mfma_f32_16x16x32_bf16(ah[mt], bhh8, a2, 0, 0, 0);
                        a2 = __builtin_amdgcn_mfma_f32_16x16x32_bf16(ah[mt], bhl8, a2, 0, 0, 0);
                        acc[mt][nt] = a2;
                    }
                }
            }
#pragma unroll
            for (int mt = 0; mt < 4; ++mt)
#pragma unroll
                for (int nt = 0; nt < 2; ++nt) {
                    const float bb = bi_z[nt] + bh_z[nt];
#pragma unroll
                    for (int r = 0; r < 4; ++r)
                        rz[mt][nt][r] |= ((uint32_t)f2bf(sigmoidf_(acc[mt][nt][r] + bb))) << 16;
                }
        }
        // n gate (cols 256..383): separate i/h accumulators
        f32x4 acc_i[4][2], acc_h[4][2];
#pragma unroll
        for (int mt = 0; mt < 4; ++mt)
#pragma unroll
            for (int nt = 0; nt < 2; ++nt) {
                acc_i[mt][nt] = (f32x4){0.f, 0.f, 0.f, 0.f};
                acc_h[mt][nt] = (f32x4){0.f, 0.f, 0.f, 0.f};
            }
#pragma unroll
        for (int ks = 0; ks < 4; ++ks) {
            const int k0 = ks * 32;
            bf16x8 ag[4], ah[4];
#pragma unroll
            for (int mt = 0; mt < 4; ++mt) {
                ag[mt] = *(const bf16x8*)&sG[(mt * 16 + l15) * SP + k0 + quad * 8];
                ah[mt] = *(const bf16x8*)&sH[(mt * 16 + l15) * SP + k0 + quad * 8];
            }
#pragma unroll
            for (int nt = 0; nt < 2; ++nt) {
                const size_t boff = (size_t)(256 + colbase + nt * 16 + l15) * 128 + k0 + quad * 8;
                bf16x8 bih8 = *(const bf16x8*)(wi_hi + boff);
                bf16x8 bil8 = *(const bf16x8*)(wi_lo + boff);
                bf16x8 bhh8 = *(const bf16x8*)(wh_hi + boff);
                bf16x8 bhl8 = *(const bf16x8*)(wh_lo + boff);
#pragma unroll
                for (int mt = 0; mt < 4; ++mt) {
                    acc_i[mt][nt] = __builtin_amdgcn_mfma_f32_16x16x32_bf16(ag[mt], bih8, acc_i[mt][nt], 0, 0, 0);
                    acc_i[mt][nt] = __builtin_amdgcn_mfma_f32_16x16x32_bf16(ag[mt], bil8, acc_i[mt][nt], 0, 0, 0);
                    acc_h[mt][nt] = __builtin_amdgcn_mfma_f32_16x16x32_bf16(ah[mt], bhh8, acc_h[mt][nt], 0, 0, 0);
                    acc_h[mt][nt] = __builtin_amdgcn_mfma_f32_16x16x32_bf16(ah[mt], bhl8, acc_h[mt][nt], 0, 0, 0);
                }
            }
        }

        // ---- epilogue ----
        if (layer == 0) __syncthreads();   // gates done reading sG before overwrite
#pragma unroll
        for (int mt = 0; mt < 4; ++mt)
#pragma unroll
            for (int nt = 0; nt < 2; ++nt) {
#pragma unroll
                for (int r = 0; r < 4; ++r) {
                    const int row = mt * 16 + quad * 4 + r;
                    const int c = colbase + nt * 16 + l15;
                    const float i_n = acc_i[mt][nt][r] + bi_n[nt];
                    const float h_n = acc_h[mt][nt][r] + bh_n[nt];
                    const uint32_t p = rz[mt][nt][r];
                    const float rr = bf2f((u16)(p & 0xFFFFu));
                    const float zz = bf2f((u16)(p >> 16));
                    const float nn = tanhf(i_n + rr * h_n);
                    const float hv = bf2f(sH[row * SP + c]);
                    const float out = (1.0f - zz) * nn + zz * hv;
                    if (layer == 0) sG[row * SP + c] = f2bf(out);
                    else            sum[mt][nt][r] += out;
                }
            }
        if (layer == 0) {
            __syncthreads();
            if (sgn < N_NODES) {
                const uint4* sp = (const uint4*)&sG[sn * SP + sp4 * 32];
                uint4* d = (uint4*)(hbufs[s] + (size_t)sgn * DIM + sp4 * 32);
                d[0] = sp[0]; d[1] = sp[1]; d[2] = sp[2]; d[3] = sp[3];
            }
        }
    }

    if (layer == 1) {
        __syncthreads();
        const float third = 1.0f / 3.0f;
#pragma unroll
        for (int mt = 0; mt < 4; ++mt)
#pragma unroll
            for (int nt = 0; nt < 2; ++nt) {
                const int c = colbase + nt * 16 + l15;
#pragma unroll
                for (int r = 0; r < 4; ++r)
                    sG[(mt * 16 + quad * 4 + r) * SP + c] = f2bf(sum[mt][nt][r] * third);
            }
        __syncthreads();
        if (sgn < N_NODES) {
            const uint4* sp = (const uint4*)&sG[sn * SP + sp4 * 32];
            uint4* d = (uint4*)(xout + (size_t)sgn * DIM + sp4 * 32);
            d[0] = sp[0]; d[1] = sp[1]; d[2] = sp[2]; d[3] = sp[3];
        }
    }
}

// ---------------- pooling (bf16 x) ----------------
__global__ void k_pool(const u16* __restrict__ xf, const int* __restrict__ batch,
                       float* __restrict__ pooled, int* __restrict__ gcnt) {
    const int tid = threadIdx.x;
    const int f = tid & 127;
    const int half = tid >> 7;
    const int nstart = blockIdx.x * 64 + half * 32;
    float accv = 0.0f;
    int curg = -1, cnt = 0;
    for (int t = 0; t < 32; ++t) {
        const int n = nstart + t;
        if (n >= N_NODES) break;
        const int g = batch[n];
        if (g != curg) {
            if (curg >= 0) {
                atomicAdd(&pooled[curg * DIM + f], accv);
                if (f == 0) atomicAdd(&gcnt[curg], cnt);
            }
            curg = g; accv = 0.0f; cnt = 0;
        }
        accv += bf2f(xf[(size_t)n * DIM + f]);
        cnt++;
    }
    if (curg >= 0) {
        atomicAdd(&pooled[curg * DIM + f], accv);
        if (f == 0) atomicAdd(&gcnt[curg], cnt);
    }
}

// ---------------- MLP head ----------------
__global__ void k_head(const float* __restrict__ pooled, const int* __restrict__ gcnt,
                       const float* __restrict__ ptf,
                       const float* __restrict__ fc1w, const float* __restrict__ fc1b,
                       const float* __restrict__ fc2w, const float* __restrict__ fc2b,
                       const float* __restrict__ fclw, const float* __restrict__ fclb,
                       void* __restrict__ out, const int* __restrict__ flag) {
    __shared__ float xh[64 * 129];
    __shared__ float h1[64 * 80];
    const int tid = threadIdx.x;
    for (int i = tid; i < 64 * 128; i += 256) {
        const int g = i >> 7;
        int c = gcnt[g]; if (c < 1) c = 1;
        xh[g * 129 + (i & 127)] = pooled[i] / (float)c;
    }
    for (int g = tid; g < 64; g += 256) xh[g * 129 + 128] = ptf[g];
    __syncthreads();
    for (int i = tid; i < 64 * 80; i += 256) {
        const int g = i / 80, c = i - g * 80;
        float s = fc1b[c];
        const float* xr = &xh[g * 129];
        const float* wr = &fc1w[c * 129];
        for (int k = 0; k < 129; ++k) s += xr[k] * wr[k];
        h1[i] = (s > 0.0f) ? s : 0.01f * s;
    }
    __syncthreads();
    float* h2 = xh;
    for (int i = tid; i < 64 * 80; i += 256) {
        const int g = i / 80, c = i - g * 80;
        float s = fc2b[c];
        const float* hr = &h1[g * 80];
        const float* wr = &fc2w[c * 80];
        for (int k = 0; k < 80; ++k) s += hr[k] * wr[k];
        h2[i] = (s > 0.0f) ? s : 0.01f * s;
    }
    __syncthreads();
    for (int i = tid; i < 128; i += 256) {
        const int g = i >> 1, c = i & 1;
        float s = fclb[c];
        const float* hr = &h2[g * 80];
        const float* wr = &fclw[c * 80];
        for (int k = 0; k < 80; ++k) s += hr[k] * wr[k];
        if (*flag) ((u16*)out)[i] = f2bf(s);
        else       ((float*)out)[i] = s;
    }
}

// ---------------- launcher ----------------
extern "C" void kernel_launch(void* const* d_in, const int* in_sizes, int n_in,
                              void* d_out, int out_size, void* d_ws, size_t ws_size,
                              hipStream_t stream) {
    if (n_in < 16) return;
    const void* x_in    = d_in[0];
    const int*  ei      = (const int*)d_in[1];
    const int*  attr    = (const int*)d_in[2];
    const int*  batch   = (const int*)d_in[3];
    const void* pt_in   = d_in[4];
    const void* W_in    = d_in[5];
    const void* wih_in  = d_in[6];
    const void* whh_in  = d_in[7];
    const void* bih_in  = d_in[8];
    const void* bhh_in  = d_in[9];
    const void* fc1w_in = d_in[10];
    const void* fc1b_in = d_in[11];
    const void* fc2w_in = d_in[12];
    const void* fc2b_in = d_in[13];
    const void* fclw_in = d_in[14];
    const void* fclb_in = d_in[15];

    char* ws = (char*)d_ws;
    size_t o = 0;
    auto alloc = [&](size_t b) { size_t r = o; o += (b + 255) & ~(size_t)255; return r; };

    const size_t o_flag   = alloc(4);
    const size_t o_xbf    = alloc((size_t)N_NODES * DIM * 2);
    const size_t o_h0     = alloc((size_t)N_NODES * DIM * 2);
    const size_t o_h1     = alloc((size_t)N_NODES * DIM * 2);
    const size_t o_h2     = alloc((size_t)N_NODES * DIM * 2);
    const size_t o_Wt_hi  = alloc((size_t)NSETS * NLAYERS * DIM * DIM * 2);
    const size_t o_Wt_lo  = alloc((size_t)NSETS * NLAYERS * DIM * DIM * 2);
    const size_t o_wih_hi = alloc((size_t)NSETS * 384 * DIM * 2);
    const size_t o_wih_lo = alloc((size_t)NSETS * 384 * DIM * 2);
    const size_t o_whh_hi = alloc((size_t)NSETS * 384 * DIM * 2);
    const size_t o_whh_lo = alloc((size_t)NSETS * 384 * DIM * 2);
    const size_t o_bih    = alloc((size_t)NSETS * 384 * 4);
    const size_t o_bhh    = alloc((size_t)NSETS * 384 * 4);
    const size_t o_fc1w   = alloc(10320 * 4);
    const size_t o_fc1b   = alloc(80 * 4);
    const size_t o_fc2w   = alloc(6400 * 4);
    const size_t o_fc2b   = alloc(80 * 4);
    const size_t o_fclw   = alloc(160 * 4);
    const size_t o_fclb   = alloc(2 * 4);
    const size_t o_ptf    = alloc(64 * 4);
    const size_t o_cnt    = alloc((size_t)3 * N_NODES * 4);
    const size_t o_cursor = alloc((size_t)3 * N_NODES * 4);
    const size_t o_rp     = alloc(((size_t)3 * N_NODES + 1) * 4);
    const size_t o_col    = alloc((size_t)N_EDGES * 4);
    const int    nb_scan  = (3 * N_NODES + 1023) / 1024;
    const size_t o_part   = alloc((size_t)nb_scan * 4);
    const size_t o_pooled = alloc((size_t)NGRAPH * DIM * 4);
    const size_t o_gcnt   = alloc((size_t)NGRAPH * 4);

    if (ws_size < o) {
        fprintf(stderr, "GGNN kernel: workspace too small: need %zu, have %zu\n", o, ws_size);
        return;
    }

    int*   flag   = (int*)(ws + o_flag);
    u16*   xbf    = (u16*)(ws + o_xbf);
    u16*   h0     = (u16*)(ws + o_h0);
    u16*   h1     = (u16*)(ws + o_h1);
    u16*   h2     = (u16*)(ws + o_h2);
    u16*   Wt_hi  = (u16*)(ws + o_Wt_hi);
    u16*   Wt_lo  = (u16*)(ws + o_Wt_lo);
    u16*   wih_hi = (u16*)(ws + o_wih_hi);
    u16*   wih_lo = (u16*)(ws + o_wih_lo);
    u16*   whh_hi = (u16*)(ws + o_whh_hi);
    u16*   whh_lo = (u16*)(ws + o_whh_lo);
    float* bihf   = (float*)(ws + o_bih);
    float* bhhf   = (float*)(ws + o_bhh);
    float* fc1wf  = (float*)(ws + o_fc1w);
    float* fc1bf  = (float*)(ws + o_fc1b);
    float* fc2wf  = (float*)(ws + o_fc2w);
    float* fc2bf  = (float*)(ws + o_fc2b);
    float* fclwf  = (float*)(ws + o_fclw);
    float* fclbf  = (float*)(ws + o_fclb);
    float* ptf    = (float*)(ws + o_ptf);
    int*   cnt    = (int*)(ws + o_cnt);
    int*   cursor = (int*)(ws + o_cursor);
    int*   rp     = (int*)(ws + o_rp);
    int*   col    = (int*)(ws + o_col);
    int*   part   = (int*)(ws + o_part);
    float* pooled = (float*)(ws + o_pooled);
    int*   gcnt   = (int*)(ws + o_gcnt);

    hipMemsetAsync(cnt, 0, (size_t)3 * N_NODES * 4, stream);
    hipMemsetAsync(pooled, 0, (o_gcnt - o_pooled) + (size_t)NGRAPH * 4, stream);

    k_detect<<<1, 256, 0, stream>>>((const u16*)x_in, flag);

    // converts + weight prep
    k_to_bf<<<(N_NODES * DIM + 2047) / 2048, 256, 0, stream>>>(x_in, xbf, N_NODES * DIM, flag);
    k_prep_W<<<(NSETS * NLAYERS * DIM * DIM + 255) / 256, 256, 0, stream>>>(W_in, Wt_hi, Wt_lo, flag);
    k_prep_G<<<(NSETS * 384 * DIM + 255) / 256, 256, 0, stream>>>(wih_in, wih_hi, wih_lo, flag);
    k_prep_G<<<(NSETS * 384 * DIM + 255) / 256, 256, 0, stream>>>(whh_in, whh_hi, whh_lo, flag);
    k_convert<<<(NSETS * 384 + 255) / 256, 256, 0, stream>>>(bih_in, bihf, NSETS * 384, flag);
    k_convert<<<(NSETS * 384 + 255) / 256, 256, 0, stream>>>(bhh_in, bhhf, NSETS * 384, flag);
    k_convert<<<(10320 + 255) / 256, 256, 0, stream>>>(fc1w_in, fc1wf, 10320, flag);
    k_convert<<<1, 256, 0, stream>>>(fc1b_in, fc1bf, 80, flag);
    k_convert<<<(6400 + 255) / 256, 256, 0, stream>>>(fc2w_in, fc2wf, 6400, flag);
    k_convert<<<1, 256, 0, stream>>>(fc2b_in, fc2bf, 80, flag);
    k_convert<<<1, 256, 0, stream>>>(fclw_in, fclwf, 160, flag);
    k_convert<<<1, 256, 0, stream>>>(fclb_in, fclbf, 2, flag);
    k_convert<<<1, 256, 0, stream>>>(pt_in, ptf, 64, flag);

    // CSR build
    k_deg<<<(N_EDGES + 255) / 256, 256, 0, stream>>>(ei, attr, cnt);
    k_scan1<<<nb_scan, 1024, 0, stream>>>(cnt, rp, part, 3 * N_NODES);
    k_scan2<<<1, 1024, 0, stream>>>(part, nb_scan);
    k_scan3<<<nb_scan, 1024, 0, stream>>>(rp, cursor, part, 3 * N_NODES);
    k_fill<<<(N_EDGES + 255) / 256, 256, 0, stream>>>(ei, attr, cursor, col);

    // fused GGC passes: 2 passes x 2 layers
    const int NB = (N_NODES + 63) / 64;
    for (int pass = 0; pass < NPASS; ++pass) {
        k_step<<<NB, 256, 0, stream>>>(xbf, h0, h1, h2, xbf,
                                       Wt_hi, Wt_lo, wih_hi, wih_lo, whh_hi, whh_lo,
                                       bihf, bhhf, rp, col, 0);
        k_step<<<NB, 256, 0, stream>>>(xbf, h0, h1, h2, xbf,
                                       Wt_hi, Wt_lo, wih_hi, wih_lo, whh_hi, whh_lo,
                                       bihf, bhhf, rp, col, 1);
    }

    // pooling + head
    k_pool<<<NB, 256, 0, stream>>>(xbf, batch, pooled, gcnt);
    k_head<<<1, 256, 0, stream>>>(pooled, gcnt, ptf, fc1wf, fc1bf, fc2wf, fc2bf,
                                  fclwf, fclbf, d_out, flag);
}